// Round 1
// baseline (3033.538 us; speedup 1.0000x reference)
//
#include <hip/hip_runtime.h>
#include <math.h>

// ---- problem constants ----
#define CH 56          // channels
#define NBD 8          // "B" depth dim
#define HH 192
#define WW 192
#define PLANE (HH*WW)          // 36864
#define S3 (NBD*PLANE)         // 294912 positions per channel
#define NWX 24                 // windows per row/col
#define NTOK 64                // tokens per window
#define DHALF 28               // q/k/v channels
#define DHEAD 14               // per-head dim
// LDS padded strides (bank-conflict avoidance)
#define XNP 57
#define QKP 29
#define SIMP 65

__device__ __forceinline__ int gidx(int c, int b, int y, int x) {
    return ((c * NBD + b) * HH + y) * WW + x;
}

// =====================================================================
// Kernel 1: FA — fused PreNorm + windowed self-attention, per (window,b)
// =====================================================================
__global__ __launch_bounds__(256) void fa_kernel(
    const float* __restrict__ x,
    const float* __restrict__ lnw, const float* __restrict__ lnb,
    const float* __restrict__ qkw, const float* __restrict__ vw,
    const float* __restrict__ ow,  const float* __restrict__ ob,
    const float* __restrict__ pcqw, const float* __restrict__ pcqb,
    const float* __restrict__ pckw, const float* __restrict__ pckb,
    const float* __restrict__ m1,  const float* __restrict__ m2a,
    const float* __restrict__ m2b,
    float* __restrict__ x1)
{
    __shared__ float s_xn[NTOK * XNP];          // LN'd window [tok][c]
    __shared__ float s_w[56*56 + 28*56];        // qk_w rows 0..55, v_w rows 56..83 (contiguous 84x56)
    __shared__ float s_q[NTOK * QKP];
    __shared__ float s_k[NTOK * QKP];
    __shared__ float s_v[NTOK * QKP];
    __shared__ float s_sim[NTOK * SIMP];
    __shared__ float s_o[NTOK * DHALF];
    __shared__ float s_mu[NTOK], s_rs[NTOK];
    __shared__ float s_Sq[NTOK], s_Sk[NTOK], s_t[NTOK], s_t2[NTOK];
    __shared__ float s_theta;

    const int tid = threadIdx.x;
    const int b   = blockIdx.x & 7;
    const int win = blockIdx.x >> 3;
    const int y0  = (win / NWX) * 8;
    const int x0  = (win % NWX) * 8;

    // load window (raw) + stage projection weights
    for (int i = tid; i < NTOK * CH; i += 256) {
        int c = i >> 6, tok = i & 63;
        s_xn[tok * XNP + c] = x[gidx(c, b, y0 + (tok >> 3), x0 + (tok & 7))];
    }
    for (int i = tid; i < 84 * 56; i += 256)
        s_w[i] = (i < 3136) ? qkw[i] : vw[i - 3136];
    __syncthreads();

    // LN stats per token
    if (tid < NTOK) {
        float mu = 0.f;
        #pragma unroll
        for (int c = 0; c < CH; c++) mu += s_xn[tid * XNP + c];
        mu *= (1.f / CH);
        float var = 0.f;
        #pragma unroll
        for (int c = 0; c < CH; c++) { float d = s_xn[tid * XNP + c] - mu; var += d * d; }
        var *= (1.f / CH);
        s_mu[tid] = mu;
        s_rs[tid] = rsqrtf(var + 1e-5f);
    }
    __syncthreads();
    for (int i = tid; i < NTOK * CH; i += 256) {
        int c = i >> 6, tok = i & 63;
        s_xn[tok * XNP + c] = (s_xn[tok * XNP + c] - s_mu[tok]) * s_rs[tok] * lnw[c] + lnb[c];
    }
    __syncthreads();

    // projections: 64 tokens x 84 outputs (28 q, 28 k, 28 v)
    for (int i = tid; i < NTOK * 84; i += 256) {
        int o = i >> 6, tok = i & 63;          // wave shares o -> broadcast weight row
        const float* wr = &s_w[o * 56];
        float acc = 0.f;
        #pragma unroll
        for (int c = 0; c < CH; c++) acc += s_xn[tok * XNP + c] * wr[c];
        if (o < 28)       s_q[tok * QKP + o]        = acc;
        else if (o < 56)  s_k[tok * QKP + (o - 28)] = acc;
        else              s_v[tok * QKP + (o - 56)] = acc;
    }
    __syncthreads();
    // re-stage s_w with out_w (56x28) — not read again until epilogue
    for (int i = tid; i < 56 * 28; i += 256) s_w[i] = ow[i];

    // heads
    for (int h = 0; h < 2; h++) {
        const int ho = h * DHEAD;
        if (tid < NTOK) {
            float a = pcqb[0];
            #pragma unroll
            for (int d = 0; d < DHEAD; d++) a += s_q[tid * QKP + ho + d] * pcqw[d];
            s_Sq[tid] = a;
        } else if (tid < 2 * NTOK) {
            int j = tid - NTOK;
            float a = pckb[0];
            #pragma unroll
            for (int d = 0; d < DHEAD; d++) a += s_k[j * QKP + ho + d] * pckw[d];
            s_Sk[j] = a;
        }
        __syncthreads();
        // sim[i][j]
        for (int i = tid; i < NTOK * NTOK; i += 256) {
            int r = i >> 6, j = i & 63;
            float a = 0.f;
            #pragma unroll
            for (int d = 0; d < DHEAD; d++)
                a += s_q[r * QKP + ho + d] * s_k[j * QKP + ho + d];
            s_sim[r * SIMP + j] = a;
        }
        __syncthreads();
        // t[i] = sum_{j != i} sim[i][j]*m1[j]
        if (tid < NTOK) {
            float a = 0.f;
            for (int j = 0; j < NTOK; j++)
                if (j != tid) a += s_sim[tid * SIMP + j] * m1[j];
            s_t[tid] = a;
        }
        __syncthreads();
        // t2[j] = leaky_relu(sum_i t[i]*m2a[j][i], 0.1)
        if (tid < NTOK) {
            float a = 0.f;
            for (int i2 = 0; i2 < NTOK; i2++) a += s_t[i2] * m2a[tid * 64 + i2];
            s_t2[tid] = (a > 0.f) ? a : 0.1f * a;
        }
        __syncthreads();
        if (tid == 0) {
            float a = 0.f;
            for (int j = 0; j < NTOK; j++) a += s_t2[j] * m2b[j];
            s_theta = a;
        }
        __syncthreads();
        // sims = sim*Sq[i]*Sk[j]; attn = softmax(sims) * (sims > theta)
        if (tid < NTOK) {
            const float Sqi = s_Sq[tid];
            float m = -1e30f;
            for (int j = 0; j < NTOK; j++) {
                float s = s_sim[tid * SIMP + j] * Sqi * s_Sk[j];
                s_sim[tid * SIMP + j] = s;
                m = fmaxf(m, s);
            }
            float sum = 0.f;
            for (int j = 0; j < NTOK; j++) sum += expf(s_sim[tid * SIMP + j] - m);
            const float inv = 1.f / sum, th = s_theta;
            for (int j = 0; j < NTOK; j++) {
                float s = s_sim[tid * SIMP + j];
                s_sim[tid * SIMP + j] = (s > th) ? expf(s - m) * inv : 0.f;
            }
        }
        __syncthreads();
        // out[i][d] = sum_j attn[i][j]*v[j][d]
        for (int i = tid; i < NTOK * DHEAD; i += 256) {
            int r = i / DHEAD, d = i - r * DHEAD;
            float a = 0.f;
            #pragma unroll
            for (int j = 0; j < NTOK; j++)
                a += s_sim[r * SIMP + j] * s_v[j * QKP + ho + d];
            s_o[r * DHALF + ho + d] = a;
        }
        __syncthreads();
    }

    // epilogue: out-proj + bias + residual
    for (int i = tid; i < NTOK * CH; i += 256) {
        int c = i >> 6, tok = i & 63;
        float a = ob[c];
        #pragma unroll
        for (int o = 0; o < DHALF; o++) a += s_o[tok * DHALF + o] * s_w[c * DHALF + o];
        int g = gidx(c, b, y0 + (tok >> 3), x0 + (tok & 7));
        x1[g] = a + x[g];
    }
}

// =====================================================================
// Kernel 2: LayerNorm over channel dim, register-resident
// =====================================================================
__global__ __launch_bounds__(256) void ln_kernel(
    const float* __restrict__ in, const float* __restrict__ w,
    const float* __restrict__ b, float* __restrict__ outp)
{
    int p = blockIdx.x * 256 + threadIdx.x;
    if (p >= S3) return;
    float v[CH];
    float mu = 0.f;
    #pragma unroll
    for (int c = 0; c < CH; c++) { v[c] = in[(size_t)c * S3 + p]; mu += v[c]; }
    mu *= (1.f / CH);
    float var = 0.f;
    #pragma unroll
    for (int c = 0; c < CH; c++) { float d = v[c] - mu; var += d * d; }
    float rs = rsqrtf(var * (1.f / CH) + 1e-5f);
    #pragma unroll
    for (int c = 0; c < CH; c++)
        outp[(size_t)c * S3 + p] = (v[c] - mu) * rs * w[c] + b[c];
}

// =====================================================================
// Kernel 3: grouped 3x3x3 conv, 2-in -> 1-out per group (28 out ch)
// =====================================================================
__global__ __launch_bounds__(256) void conv3_kernel(
    const float* __restrict__ in, const float* __restrict__ w,
    float* __restrict__ outp)
{
    int n = blockIdx.x * 256 + threadIdx.x;
    if (n >= DHALF * S3) return;
    int o = n / S3;
    int r = n - o * S3;
    int z = r / PLANE;
    int t = r - z * PLANE;
    int y = t / WW;
    int xx = t - y * WW;
    float acc = 0.f;
    #pragma unroll
    for (int ic = 0; ic < 2; ic++) {
        const float* ip = in + (size_t)(2 * o + ic) * S3;
        const float* wp = w + (o * 2 + ic) * 27;
        #pragma unroll
        for (int dz = 0; dz < 3; dz++) {
            int zz = z + dz - 1;
            if (zz < 0 || zz >= NBD) continue;
            #pragma unroll
            for (int dy = 0; dy < 3; dy++) {
                int yy = y + dy - 1;
                if (yy < 0 || yy >= HH) continue;
                #pragma unroll
                for (int dx = 0; dx < 3; dx++) {
                    int xc = xx + dx - 1;
                    if (xc < 0 || xc >= WW) continue;
                    acc += ip[zz * PLANE + yy * WW + xc] * wp[dz * 9 + dy * 3 + dx];
                }
            }
        }
    }
    outp[n] = acc;
}

// =====================================================================
// Kernel 4: SCA — windowed cross-attention on precomputed q,k,v
// =====================================================================
__global__ __launch_bounds__(256) void sca_kernel(
    const float* __restrict__ qb, const float* __restrict__ kb,
    const float* __restrict__ vb, const float* __restrict__ x1,
    const float* __restrict__ ocw,
    const float* __restrict__ pcqw, const float* __restrict__ pcqb,
    const float* __restrict__ pckw, const float* __restrict__ pckb,
    const float* __restrict__ m1,  const float* __restrict__ m2a,
    const float* __restrict__ m2b,
    float* __restrict__ x2)
{
    __shared__ float s_q[NTOK * QKP];
    __shared__ float s_k[NTOK * QKP];
    __shared__ float s_v[NTOK * QKP];
    __shared__ float s_sim[NTOK * SIMP];
    __shared__ float s_o[NTOK * DHALF];
    __shared__ float s_Sq[NTOK], s_Sk[NTOK], s_t[NTOK], s_t2[NTOK];
    __shared__ float s_theta;

    const int tid = threadIdx.x;
    const int b   = blockIdx.x & 7;
    const int win = blockIdx.x >> 3;
    const int y0  = (win / NWX) * 8;
    const int x0  = (win % NWX) * 8;

    for (int i = tid; i < NTOK * DHALF; i += 256) {
        int o = i >> 6, tok = i & 63;
        int g = ((o * NBD + b) * HH + y0 + (tok >> 3)) * WW + x0 + (tok & 7);
        s_q[tok * QKP + o] = qb[g];
        s_k[tok * QKP + o] = kb[g];
        s_v[tok * QKP + o] = vb[g];
    }
    __syncthreads();

    for (int h = 0; h < 2; h++) {
        const int ho = h * DHEAD;
        if (tid < NTOK) {
            float a = pcqb[0];
            #pragma unroll
            for (int d = 0; d < DHEAD; d++) a += s_q[tid * QKP + ho + d] * pcqw[d];
            s_Sq[tid] = a;
        } else if (tid < 2 * NTOK) {
            int j = tid - NTOK;
            float a = pckb[0];
            #pragma unroll
            for (int d = 0; d < DHEAD; d++) a += s_k[j * QKP + ho + d] * pckw[d];
            s_Sk[j] = a;
        }
        __syncthreads();
        for (int i = tid; i < NTOK * NTOK; i += 256) {
            int r = i >> 6, j = i & 63;
            float a = 0.f;
            #pragma unroll
            for (int d = 0; d < DHEAD; d++)
                a += s_q[r * QKP + ho + d] * s_k[j * QKP + ho + d];
            s_sim[r * SIMP + j] = a;
        }
        __syncthreads();
        if (tid < NTOK) {
            float a = 0.f;
            for (int j = 0; j < NTOK; j++)
                if (j != tid) a += s_sim[tid * SIMP + j] * m1[j];
            s_t[tid] = a;
        }
        __syncthreads();
        if (tid < NTOK) {
            float a = 0.f;
            for (int i2 = 0; i2 < NTOK; i2++) a += s_t[i2] * m2a[tid * 64 + i2];
            s_t2[tid] = (a > 0.f) ? a : 0.1f * a;
        }
        __syncthreads();
        if (tid == 0) {
            float a = 0.f;
            for (int j = 0; j < NTOK; j++) a += s_t2[j] * m2b[j];
            s_theta = a;
        }
        __syncthreads();
        if (tid < NTOK) {
            const float Sqi = s_Sq[tid];
            float m = -1e30f;
            for (int j = 0; j < NTOK; j++) {
                float s = s_sim[tid * SIMP + j] * Sqi * s_Sk[j];
                s_sim[tid * SIMP + j] = s;
                m = fmaxf(m, s);
            }
            float sum = 0.f;
            for (int j = 0; j < NTOK; j++) sum += expf(s_sim[tid * SIMP + j] - m);
            const float inv = 1.f / sum, th = s_theta;
            for (int j = 0; j < NTOK; j++) {
                float s = s_sim[tid * SIMP + j];
                s_sim[tid * SIMP + j] = (s > th) ? expf(s - m) * inv : 0.f;
            }
        }
        __syncthreads();
        for (int i = tid; i < NTOK * DHEAD; i += 256) {
            int r = i / DHEAD, d = i - r * DHEAD;
            float a = 0.f;
            #pragma unroll
            for (int j = 0; j < NTOK; j++)
                a += s_sim[r * SIMP + j] * s_v[j * QKP + ho + d];
            s_o[r * DHALF + ho + d] = a;
        }
        __syncthreads();
    }

    // epilogue: 1x1x1 expand conv (ch o uses att ch o/2) + residual
    for (int i = tid; i < NTOK * CH; i += 256) {
        int c = i >> 6, tok = i & 63;
        int g = gidx(c, b, y0 + (tok >> 3), x0 + (tok & 7));
        x2[g] = s_o[tok * DHALF + (c >> 1)] * ocw[c] + x1[g];
    }
}

// =====================================================================
// Kernel 5: FFN — fused LN + 1x1 expand + grouped (1,3,3) conv + GELU gate
// one block per (z, 8x8 tile); 10x10 halo in LDS
// =====================================================================
__global__ __launch_bounds__(256) void ffn_kernel(
    const float* __restrict__ x2, const float* __restrict__ last,
    const float* __restrict__ ln1w, const float* __restrict__ ln1b,
    const float* __restrict__ ln2w, const float* __restrict__ ln2b,
    const float* __restrict__ w1x, const float* __restrict__ w2x,
    const float* __restrict__ w1l, const float* __restrict__ w2l,
    float* __restrict__ outp)
{
    __shared__ float s_a[CH * 100];
    __shared__ float s_b[CH * 100];
    __shared__ float s_h[2][4 * 100];
    __shared__ float s_mu[2][100], s_rs[2][100];

    const int tid = threadIdx.x;
    const int z  = blockIdx.x / 576;
    const int t  = blockIdx.x % 576;
    const int ty = t / 24, tx = t % 24;
    const int yb = ty * 8 - 1, xb0 = tx * 8 - 1;

    for (int i = tid; i < CH * 100; i += 256) {
        int c = i / 100, p = i - c * 100;
        int y = yb + p / 10, xx = xb0 + (p % 10);
        bool v = (y >= 0 && y < HH && xx >= 0 && xx < WW);
        float av = 0.f, bv = 0.f;
        if (v) {
            int g = ((c * NBD + z) * HH + y) * WW + xx;
            av = x2[g];
            bv = last[g];
        }
        s_a[i] = av;
        s_b[i] = bv;
    }
    __syncthreads();
    if (tid < 200) {
        int which = tid / 100, p = tid % 100;
        const float* s = which ? s_b : s_a;
        int y = yb + p / 10, xx = xb0 + (p % 10);
        bool v = (y >= 0 && y < HH && xx >= 0 && xx < WW);
        float mu = 0.f, var = 0.f, rs = 0.f;
        if (v) {
            for (int c = 0; c < CH; c++) mu += s[c * 100 + p];
            mu *= (1.f / CH);
            for (int c = 0; c < CH; c++) { float d = s[c * 100 + p] - mu; var += d * d; }
            rs = rsqrtf(var * (1.f / CH) + 1e-5f);
        }
        s_mu[which][p] = mu;
        s_rs[which][p] = rs;
    }
    __syncthreads();
    for (int i = tid; i < CH * 100; i += 256) {
        int c = i / 100, p = i - c * 100;
        float ra = s_rs[0][p], rb = s_rs[1][p];
        s_a[i] = (ra > 0.f) ? (s_a[i] - s_mu[0][p]) * ra * ln1w[c] + ln1b[c] : 0.f;
        s_b[i] = (rb > 0.f) ? (s_b[i] - s_mu[1][p]) * rb * ln2w[c] + ln2b[c] : 0.f;
    }
    __syncthreads();

    for (int o = 0; o < CH; o++) {
        // hidden channels 4o..4o+3 for both branches on 10x10 halo
        for (int i = tid; i < 800; i += 256) {
            int br = i / 400;
            int rem = i - br * 400;
            int j = rem / 100, p = rem - j * 100;
            const float* wr = (br ? w1l : w1x) + (o * 4 + j) * 56;
            const float* si = br ? s_b : s_a;
            float acc = 0.f;
            #pragma unroll
            for (int c = 0; c < CH; c++) acc += si[c * 100 + p] * wr[c];
            s_h[br][j * 100 + p] = acc;
        }
        __syncthreads();
        if (tid < 64) {
            int oy = tid / 8, ox = tid % 8;
            float xbv = 0.f, lbv = 0.f;
            #pragma unroll
            for (int j = 0; j < 4; j++)
                #pragma unroll
                for (int ky = 0; ky < 3; ky++)
                    #pragma unroll
                    for (int kx = 0; kx < 3; kx++) {
                        int hp = j * 100 + (oy + ky) * 10 + ox + kx;
                        int wi = (o * 4 + j) * 9 + ky * 3 + kx;
                        xbv += s_h[0][hp] * w2x[wi];
                        lbv += s_h[1][hp] * w2l[wi];
                    }
            float ge = 0.5f * lbv * (1.f + erff(lbv * 0.70710678118654752f));
            int g = ((o * NBD + z) * HH + ty * 8 + oy) * WW + tx * 8 + ox;
            outp[g] = xbv * ge + x2[g];
        }
        __syncthreads();
    }
}

// =====================================================================
extern "C" void kernel_launch(void* const* d_in, const int* in_sizes, int n_in,
                              void* d_out, int out_size, void* d_ws, size_t ws_size,
                              hipStream_t stream)
{
    (void)in_sizes; (void)n_in; (void)out_size; (void)ws_size;
    const float* x         = (const float*)d_in[0];
    const float* last      = (const float*)d_in[1];
    const float* fa_ln_w   = (const float*)d_in[2];
    const float* fa_ln_b   = (const float*)d_in[3];
    const float* fa_qk_w   = (const float*)d_in[4];
    const float* fa_v_w    = (const float*)d_in[5];
    const float* fa_out_w  = (const float*)d_in[6];
    const float* fa_out_b  = (const float*)d_in[7];
    const float* fa_pcq_w  = (const float*)d_in[8];
    const float* fa_pcq_b  = (const float*)d_in[9];
    const float* fa_pck_w  = (const float*)d_in[10];
    const float* fa_pck_b  = (const float*)d_in[11];
    const float* fa_m1_w   = (const float*)d_in[12];
    const float* fa_m2a_w  = (const float*)d_in[13];
    const float* fa_m2b_w  = (const float*)d_in[14];
    const float* sca_ln1_w = (const float*)d_in[15];
    const float* sca_ln1_b = (const float*)d_in[16];
    const float* sca_ln2_w = (const float*)d_in[17];
    const float* sca_ln2_b = (const float*)d_in[18];
    const float* sca_q_w   = (const float*)d_in[19];
    const float* sca_k_w   = (const float*)d_in[20];
    const float* sca_v_w   = (const float*)d_in[21];
    const float* sca_out_w = (const float*)d_in[22];
    const float* sca_pcq_w = (const float*)d_in[23];
    const float* sca_pcq_b = (const float*)d_in[24];
    const float* sca_pck_w = (const float*)d_in[25];
    const float* sca_pck_b = (const float*)d_in[26];
    const float* sca_m1_w  = (const float*)d_in[27];
    const float* sca_m2a_w = (const float*)d_in[28];
    const float* sca_m2b_w = (const float*)d_in[29];
    const float* ffn_ln1_w = (const float*)d_in[30];
    const float* ffn_ln1_b = (const float*)d_in[31];
    const float* ffn_ln2_w = (const float*)d_in[32];
    const float* ffn_ln2_b = (const float*)d_in[33];
    const float* ffn_x1_w  = (const float*)d_in[34];
    const float* ffn_x2_w  = (const float*)d_in[35];
    const float* ffn_l1_w  = (const float*)d_in[36];
    const float* ffn_l2_w  = (const float*)d_in[37];
    float* out = (float*)d_out;
    float* ws  = (float*)d_ws;

    const size_t FULL = (size_t)CH * S3;      // 16,515,072
    const size_t HALF = (size_t)DHALF * S3;   //  8,257,536
    float* x1    = ws;                        // FA output
    float* lnbuf = ws + FULL;                 // LN scratch (reused), later aliased as x2
    float* qb    = lnbuf + FULL;
    float* kb    = qb + HALF;
    float* vb    = kb + HALF;
    float* x2    = lnbuf;                     // free after convs -> SCA output
    // peak ws: 2*FULL + 3*HALF floats = 231 MB

    // --- FA ---
    fa_kernel<<<dim3(4608), dim3(256), 0, stream>>>(
        x, fa_ln_w, fa_ln_b, fa_qk_w, fa_v_w, fa_out_w, fa_out_b,
        fa_pcq_w, fa_pcq_b, fa_pck_w, fa_pck_b, fa_m1_w, fa_m2a_w, fa_m2b_w, x1);

    // --- SCA: LN + grouped convs (one LN scratch, reused) ---
    ln_kernel<<<dim3(S3 / 256), dim3(256), 0, stream>>>(x1, sca_ln1_w, sca_ln1_b, lnbuf);
    conv3_kernel<<<dim3(DHALF * S3 / 256), dim3(256), 0, stream>>>(lnbuf, sca_q_w, qb);
    ln_kernel<<<dim3(S3 / 256), dim3(256), 0, stream>>>(last, sca_ln2_w, sca_ln2_b, lnbuf);
    conv3_kernel<<<dim3(DHALF * S3 / 256), dim3(256), 0, stream>>>(lnbuf, sca_k_w, kb);
    conv3_kernel<<<dim3(DHALF * S3 / 256), dim3(256), 0, stream>>>(lnbuf, sca_v_w, vb);

    sca_kernel<<<dim3(4608), dim3(256), 0, stream>>>(
        qb, kb, vb, x1, sca_out_w,
        sca_pcq_w, sca_pcq_b, sca_pck_w, sca_pck_b, sca_m1_w, sca_m2a_w, sca_m2b_w, x2);

    // --- FFN ---
    ffn_kernel<<<dim3(4608), dim3(256), 0, stream>>>(
        x2, last, ffn_ln1_w, ffn_ln1_b, ffn_ln2_w, ffn_ln2_b,
        ffn_x1_w, ffn_x2_w, ffn_l1_w, ffn_l2_w, out);
}

// Round 2
// 2432.824 us; speedup vs baseline: 1.2469x; 1.2469x over previous
//
#include <hip/hip_runtime.h>
#include <math.h>

// ---- problem constants ----
#define CH 56          // channels
#define NBD 8          // "B" depth dim
#define HH 192
#define WW 192
#define PLANE (HH*WW)          // 36864
#define S3 (NBD*PLANE)         // 294912 positions per channel
#define NWX 24                 // windows per row/col
#define NTOK 64                // tokens per window
#define DHALF 28               // q/k/v channels
#define DHEAD 14               // per-head dim
// LDS padded strides (bank-conflict avoidance)
#define XNP 57
#define QKP 29
#define SIMP 65

__device__ __forceinline__ int gidx(int c, int b, int y, int x) {
    return ((c * NBD + b) * HH + y) * WW + x;
}

// =====================================================================
// Kernel 1: FA — fused PreNorm + windowed self-attention, per (window,b)
// =====================================================================
__global__ __launch_bounds__(256) void fa_kernel(
    const float* __restrict__ x,
    const float* __restrict__ lnw, const float* __restrict__ lnb,
    const float* __restrict__ qkw, const float* __restrict__ vw,
    const float* __restrict__ ow,  const float* __restrict__ ob,
    const float* __restrict__ pcqw, const float* __restrict__ pcqb,
    const float* __restrict__ pckw, const float* __restrict__ pckb,
    const float* __restrict__ m1,  const float* __restrict__ m2a,
    const float* __restrict__ m2b,
    float* __restrict__ x1)
{
    __shared__ float s_xn[NTOK * XNP];          // LN'd window [tok][c]
    __shared__ float s_w[56*56 + 28*56];        // qk_w rows 0..55, v_w rows 56..83
    __shared__ float s_q[NTOK * QKP];
    __shared__ float s_k[NTOK * QKP];
    __shared__ float s_v[NTOK * QKP];
    __shared__ float s_sim[NTOK * SIMP];
    __shared__ float s_o[NTOK * DHALF];
    __shared__ float s_mu[NTOK], s_rs[NTOK];
    __shared__ float s_Sq[NTOK], s_Sk[NTOK], s_t[NTOK], s_t2[NTOK];
    __shared__ float s_theta;

    const int tid = threadIdx.x;
    const int b   = blockIdx.x & 7;
    const int win = blockIdx.x >> 3;
    const int y0  = (win / NWX) * 8;
    const int x0  = (win % NWX) * 8;

    for (int i = tid; i < NTOK * CH; i += 256) {
        int c = i >> 6, tok = i & 63;
        s_xn[tok * XNP + c] = x[gidx(c, b, y0 + (tok >> 3), x0 + (tok & 7))];
    }
    for (int i = tid; i < 84 * 56; i += 256)
        s_w[i] = (i < 3136) ? qkw[i] : vw[i - 3136];
    __syncthreads();

    if (tid < NTOK) {
        float mu = 0.f;
        #pragma unroll
        for (int c = 0; c < CH; c++) mu += s_xn[tid * XNP + c];
        mu *= (1.f / CH);
        float var = 0.f;
        #pragma unroll
        for (int c = 0; c < CH; c++) { float d = s_xn[tid * XNP + c] - mu; var += d * d; }
        var *= (1.f / CH);
        s_mu[tid] = mu;
        s_rs[tid] = rsqrtf(var + 1e-5f);
    }
    __syncthreads();
    for (int i = tid; i < NTOK * CH; i += 256) {
        int c = i >> 6, tok = i & 63;
        s_xn[tok * XNP + c] = (s_xn[tok * XNP + c] - s_mu[tok]) * s_rs[tok] * lnw[c] + lnb[c];
    }
    __syncthreads();

    for (int i = tid; i < NTOK * 84; i += 256) {
        int o = i >> 6, tok = i & 63;
        const float* wr = &s_w[o * 56];
        float acc = 0.f;
        #pragma unroll
        for (int c = 0; c < CH; c++) acc += s_xn[tok * XNP + c] * wr[c];
        if (o < 28)       s_q[tok * QKP + o]        = acc;
        else if (o < 56)  s_k[tok * QKP + (o - 28)] = acc;
        else              s_v[tok * QKP + (o - 56)] = acc;
    }
    __syncthreads();
    for (int i = tid; i < 56 * 28; i += 256) s_w[i] = ow[i];

    for (int h = 0; h < 2; h++) {
        const int ho = h * DHEAD;
        if (tid < NTOK) {
            float a = pcqb[0];
            #pragma unroll
            for (int d = 0; d < DHEAD; d++) a += s_q[tid * QKP + ho + d] * pcqw[d];
            s_Sq[tid] = a;
        } else if (tid < 2 * NTOK) {
            int j = tid - NTOK;
            float a = pckb[0];
            #pragma unroll
            for (int d = 0; d < DHEAD; d++) a += s_k[j * QKP + ho + d] * pckw[d];
            s_Sk[j] = a;
        }
        __syncthreads();
        for (int i = tid; i < NTOK * NTOK; i += 256) {
            int r = i >> 6, j = i & 63;
            float a = 0.f;
            #pragma unroll
            for (int d = 0; d < DHEAD; d++)
                a += s_q[r * QKP + ho + d] * s_k[j * QKP + ho + d];
            s_sim[r * SIMP + j] = a;
        }
        __syncthreads();
        if (tid < NTOK) {
            float a = 0.f;
            for (int j = 0; j < NTOK; j++)
                if (j != tid) a += s_sim[tid * SIMP + j] * m1[j];
            s_t[tid] = a;
        }
        __syncthreads();
        if (tid < NTOK) {
            float a = 0.f;
            for (int i2 = 0; i2 < NTOK; i2++) a += s_t[i2] * m2a[tid * 64 + i2];
            s_t2[tid] = (a > 0.f) ? a : 0.1f * a;
        }
        __syncthreads();
        if (tid == 0) {
            float a = 0.f;
            for (int j = 0; j < NTOK; j++) a += s_t2[j] * m2b[j];
            s_theta = a;
        }
        __syncthreads();
        if (tid < NTOK) {
            const float Sqi = s_Sq[tid];
            float m = -1e30f;
            for (int j = 0; j < NTOK; j++) {
                float s = s_sim[tid * SIMP + j] * Sqi * s_Sk[j];
                s_sim[tid * SIMP + j] = s;
                m = fmaxf(m, s);
            }
            float sum = 0.f;
            for (int j = 0; j < NTOK; j++) sum += expf(s_sim[tid * SIMP + j] - m);
            const float inv = 1.f / sum, th = s_theta;
            for (int j = 0; j < NTOK; j++) {
                float s = s_sim[tid * SIMP + j];
                s_sim[tid * SIMP + j] = (s > th) ? expf(s - m) * inv : 0.f;
            }
        }
        __syncthreads();
        for (int i = tid; i < NTOK * DHEAD; i += 256) {
            int r = i / DHEAD, d = i - r * DHEAD;
            float a = 0.f;
            #pragma unroll
            for (int j = 0; j < NTOK; j++)
                a += s_sim[r * SIMP + j] * s_v[j * QKP + ho + d];
            s_o[r * DHALF + ho + d] = a;
        }
        __syncthreads();
    }

    for (int i = tid; i < NTOK * CH; i += 256) {
        int c = i >> 6, tok = i & 63;
        float a = ob[c];
        #pragma unroll
        for (int o = 0; o < DHALF; o++) a += s_o[tok * DHALF + o] * s_w[c * DHALF + o];
        int g = gidx(c, b, y0 + (tok >> 3), x0 + (tok & 7));
        x1[g] = a + x[g];
    }
}

// =====================================================================
// Kernel 2: LayerNorm over channel dim, register-resident
// =====================================================================
__global__ __launch_bounds__(256) void ln_kernel(
    const float* __restrict__ in, const float* __restrict__ w,
    const float* __restrict__ b, float* __restrict__ outp)
{
    int p = blockIdx.x * 256 + threadIdx.x;
    if (p >= S3) return;
    float v[CH];
    float mu = 0.f;
    #pragma unroll
    for (int c = 0; c < CH; c++) { v[c] = in[(size_t)c * S3 + p]; mu += v[c]; }
    mu *= (1.f / CH);
    float var = 0.f;
    #pragma unroll
    for (int c = 0; c < CH; c++) { float d = v[c] - mu; var += d * d; }
    float rs = rsqrtf(var * (1.f / CH) + 1e-5f);
    #pragma unroll
    for (int c = 0; c < CH; c++)
        outp[(size_t)c * S3 + p] = (v[c] - mu) * rs * w[c] + b[c];
}

// =====================================================================
// Kernel 3: grouped 3x3x3 conv, 2-in -> 1-out per group (28 out ch)
// =====================================================================
__global__ __launch_bounds__(256) void conv3_kernel(
    const float* __restrict__ in, const float* __restrict__ w,
    float* __restrict__ outp)
{
    int n = blockIdx.x * 256 + threadIdx.x;
    if (n >= DHALF * S3) return;
    int o = n / S3;
    int r = n - o * S3;
    int z = r / PLANE;
    int t = r - z * PLANE;
    int y = t / WW;
    int xx = t - y * WW;
    float acc = 0.f;
    #pragma unroll
    for (int ic = 0; ic < 2; ic++) {
        const float* ip = in + (size_t)(2 * o + ic) * S3;
        const float* wp = w + (o * 2 + ic) * 27;
        #pragma unroll
        for (int dz = 0; dz < 3; dz++) {
            int zz = z + dz - 1;
            if (zz < 0 || zz >= NBD) continue;
            #pragma unroll
            for (int dy = 0; dy < 3; dy++) {
                int yy = y + dy - 1;
                if (yy < 0 || yy >= HH) continue;
                #pragma unroll
                for (int dx = 0; dx < 3; dx++) {
                    int xc = xx + dx - 1;
                    if (xc < 0 || xc >= WW) continue;
                    acc += ip[zz * PLANE + yy * WW + xc] * wp[dz * 9 + dy * 3 + dx];
                }
            }
        }
    }
    outp[n] = acc;
}

// =====================================================================
// Kernel 4: SCA — windowed cross-attention on precomputed q,k,v
// =====================================================================
__global__ __launch_bounds__(256) void sca_kernel(
    const float* __restrict__ qb, const float* __restrict__ kb,
    const float* __restrict__ vb, const float* __restrict__ x1,
    const float* __restrict__ ocw,
    const float* __restrict__ pcqw, const float* __restrict__ pcqb,
    const float* __restrict__ pckw, const float* __restrict__ pckb,
    const float* __restrict__ m1,  const float* __restrict__ m2a,
    const float* __restrict__ m2b,
    float* __restrict__ x2)
{
    __shared__ float s_q[NTOK * QKP];
    __shared__ float s_k[NTOK * QKP];
    __shared__ float s_v[NTOK * QKP];
    __shared__ float s_sim[NTOK * SIMP];
    __shared__ float s_o[NTOK * DHALF];
    __shared__ float s_Sq[NTOK], s_Sk[NTOK], s_t[NTOK], s_t2[NTOK];
    __shared__ float s_theta;

    const int tid = threadIdx.x;
    const int b   = blockIdx.x & 7;
    const int win = blockIdx.x >> 3;
    const int y0  = (win / NWX) * 8;
    const int x0  = (win % NWX) * 8;

    for (int i = tid; i < NTOK * DHALF; i += 256) {
        int o = i >> 6, tok = i & 63;
        int g = ((o * NBD + b) * HH + y0 + (tok >> 3)) * WW + x0 + (tok & 7);
        s_q[tok * QKP + o] = qb[g];
        s_k[tok * QKP + o] = kb[g];
        s_v[tok * QKP + o] = vb[g];
    }
    __syncthreads();

    for (int h = 0; h < 2; h++) {
        const int ho = h * DHEAD;
        if (tid < NTOK) {
            float a = pcqb[0];
            #pragma unroll
            for (int d = 0; d < DHEAD; d++) a += s_q[tid * QKP + ho + d] * pcqw[d];
            s_Sq[tid] = a;
        } else if (tid < 2 * NTOK) {
            int j = tid - NTOK;
            float a = pckb[0];
            #pragma unroll
            for (int d = 0; d < DHEAD; d++) a += s_k[j * QKP + ho + d] * pckw[d];
            s_Sk[j] = a;
        }
        __syncthreads();
        for (int i = tid; i < NTOK * NTOK; i += 256) {
            int r = i >> 6, j = i & 63;
            float a = 0.f;
            #pragma unroll
            for (int d = 0; d < DHEAD; d++)
                a += s_q[r * QKP + ho + d] * s_k[j * QKP + ho + d];
            s_sim[r * SIMP + j] = a;
        }
        __syncthreads();
        if (tid < NTOK) {
            float a = 0.f;
            for (int j = 0; j < NTOK; j++)
                if (j != tid) a += s_sim[tid * SIMP + j] * m1[j];
            s_t[tid] = a;
        }
        __syncthreads();
        if (tid < NTOK) {
            float a = 0.f;
            for (int i2 = 0; i2 < NTOK; i2++) a += s_t[i2] * m2a[tid * 64 + i2];
            s_t2[tid] = (a > 0.f) ? a : 0.1f * a;
        }
        __syncthreads();
        if (tid == 0) {
            float a = 0.f;
            for (int j = 0; j < NTOK; j++) a += s_t2[j] * m2b[j];
            s_theta = a;
        }
        __syncthreads();
        if (tid < NTOK) {
            const float Sqi = s_Sq[tid];
            float m = -1e30f;
            for (int j = 0; j < NTOK; j++) {
                float s = s_sim[tid * SIMP + j] * Sqi * s_Sk[j];
                s_sim[tid * SIMP + j] = s;
                m = fmaxf(m, s);
            }
            float sum = 0.f;
            for (int j = 0; j < NTOK; j++) sum += expf(s_sim[tid * SIMP + j] - m);
            const float inv = 1.f / sum, th = s_theta;
            for (int j = 0; j < NTOK; j++) {
                float s = s_sim[tid * SIMP + j];
                s_sim[tid * SIMP + j] = (s > th) ? expf(s - m) * inv : 0.f;
            }
        }
        __syncthreads();
        for (int i = tid; i < NTOK * DHEAD; i += 256) {
            int r = i / DHEAD, d = i - r * DHEAD;
            float a = 0.f;
            #pragma unroll
            for (int j = 0; j < NTOK; j++)
                a += s_sim[r * SIMP + j] * s_v[j * QKP + ho + d];
            s_o[r * DHALF + ho + d] = a;
        }
        __syncthreads();
    }

    for (int i = tid; i < NTOK * CH; i += 256) {
        int c = i >> 6, tok = i & 63;
        int g = gidx(c, b, y0 + (tok >> 3), x0 + (tok & 7));
        x2[g] = s_o[tok * DHALF + (c >> 1)] * ocw[c] + x1[g];
    }
}

// =====================================================================
// Kernel 5a: precompute collapsed FFN weights
// Weff[br][c][o][k] = sum_j w2[o][j][k] * w1[o*4+j][c]
// =====================================================================
__global__ __launch_bounds__(256) void ffn_wprep_kernel(
    const float* __restrict__ w1x, const float* __restrict__ w2x,
    const float* __restrict__ w1l, const float* __restrict__ w2l,
    float* __restrict__ weff)
{
    int idx = blockIdx.x * 256 + threadIdx.x;
    if (idx >= 2 * 28224) return;
    int br = idx / 28224;
    int rem = idx - br * 28224;
    int c = rem / 504;
    int o = (rem - c * 504) / 9;
    int k = rem - c * 504 - o * 9;
    const float* w1 = br ? w1l : w1x;
    const float* w2 = br ? w2l : w2x;
    float a = 0.f;
    #pragma unroll
    for (int j = 0; j < 4; j++)
        a += w2[(o * 4 + j) * 9 + k] * w1[(o * 4 + j) * 56 + c];
    weff[idx] = a;
}

// =====================================================================
// Kernel 5b: FFN — in-LDS LN of both inputs + collapsed dense (1,3,3)
// conv + exact-GELU gate + residual. One block per (z, 8x8 tile).
// thread = (pos 0..63, quad 0..3); quad owns output channels
// [quad*14, quad*14+14). Weight stream is wave-uniform -> s_load.
// =====================================================================
#define HLW 11          // padded halo row stride
#define HCN 110         // floats per channel halo (10 rows * 11)
__global__ __launch_bounds__(256) void ffn_kernel(
    const float* __restrict__ x2, const float* __restrict__ last,
    const float* __restrict__ ln1w, const float* __restrict__ ln1b,
    const float* __restrict__ ln2w, const float* __restrict__ ln2b,
    const float* __restrict__ weff,
    float* __restrict__ outp)
{
    __shared__ float s_in[2][CH * HCN];
    __shared__ float s_mu[2][100], s_rs[2][100];

    const int tid = threadIdx.x;
    const int z  = blockIdx.x / 576;
    const int t  = blockIdx.x % 576;
    const int ty = t / 24, tx = t % 24;
    const int yb = ty * 8 - 1, xb0 = tx * 8 - 1;

    const int pos  = tid & 63;
    const int quad = __builtin_amdgcn_readfirstlane(tid >> 6);  // wave-uniform
    const int py = pos >> 3, px = pos & 7;

    // ---- stage raw halos for both branches ----
    for (int i = tid; i < 2 * CH * 100; i += 256) {
        int br = i / 5600;
        int r = i - br * 5600;
        int c = r / 100, p = r - c * 100;
        int y = yb + p / 10, xx = xb0 + (p % 10);
        float v = 0.f;
        if (y >= 0 && y < HH && xx >= 0 && xx < WW) {
            int g = ((c * NBD + z) * HH + y) * WW + xx;
            v = br ? last[g] : x2[g];
        }
        s_in[br][c * HCN + (p / 10) * HLW + (p % 10)] = v;
    }
    __syncthreads();

    // ---- save residual (raw x2 center, own channels); LN stats ----
    float xres[14];
    #pragma unroll
    for (int oi = 0; oi < 14; oi++)
        xres[oi] = s_in[0][(quad * 14 + oi) * HCN + (py + 1) * HLW + (px + 1)];

    if (tid < 200) {
        int which = tid / 100, p = tid - which * 100;
        int y = yb + p / 10, xx = xb0 + (p % 10);
        float mu = 0.f, rs = 0.f;
        if (y >= 0 && y < HH && xx >= 0 && xx < WW) {
            const float* s = &s_in[which][(p / 10) * HLW + (p % 10)];
            for (int c = 0; c < CH; c++) mu += s[c * HCN];
            mu *= (1.f / CH);
            float var = 0.f;
            for (int c = 0; c < CH; c++) { float d = s[c * HCN] - mu; var += d * d; }
            rs = rsqrtf(var * (1.f / CH) + 1e-5f);
        }
        s_mu[which][p] = mu;
        s_rs[which][p] = rs;
    }
    __syncthreads();

    // ---- normalize in place (OOB positions stay 0) ----
    for (int i = tid; i < 2 * CH * 100; i += 256) {
        int br = i / 5600;
        int r = i - br * 5600;
        int c = r / 100, p = r - c * 100;
        float rs = s_rs[br][p];
        int a = br * (CH * HCN) + c * HCN + (p / 10) * HLW + (p % 10);
        float* sp = &s_in[0][0];
        float w = br ? ln2w[c] : ln1w[c];
        float bb = br ? ln2b[c] : ln1b[c];
        sp[a] = (rs > 0.f) ? (sp[a] - s_mu[br][p]) * rs * w + bb : 0.f;
    }
    __syncthreads();

    // ---- collapsed conv: 14 output channels per thread, both branches ----
    float accx[14], accl[14];
    #pragma unroll
    for (int oi = 0; oi < 14; oi++) { accx[oi] = 0.f; accl[oi] = 0.f; }

    const int qoff = quad * 126;                   // uniform
    const float* wx0 = weff + qoff;                // br 0 base
    const float* wl0 = weff + 28224 + qoff;        // br 1 base
    const int tbase = py * HLW + px;               // tap base (halo coords)

    for (int c = 0; c < CH; c++) {
        float ta[9], tb[9];
        const float* i0 = &s_in[0][c * HCN + tbase];
        const float* i1 = &s_in[1][c * HCN + tbase];
        #pragma unroll
        for (int ky = 0; ky < 3; ky++)
            #pragma unroll
            for (int kx = 0; kx < 3; kx++) {
                ta[ky * 3 + kx] = i0[ky * HLW + kx];
                tb[ky * 3 + kx] = i1[ky * HLW + kx];
            }
        const float* wx = wx0 + c * 504;           // uniform address stream
        const float* wl = wl0 + c * 504;
        #pragma unroll
        for (int oi = 0; oi < 14; oi++) {
            #pragma unroll
            for (int k = 0; k < 9; k++) {
                accx[oi] += ta[k] * wx[oi * 9 + k];
                accl[oi] += tb[k] * wl[oi * 9 + k];
            }
        }
    }

    // ---- gate + residual + store ----
    const int oy = ty * 8 + py, ox = tx * 8 + px;
    #pragma unroll
    for (int oi = 0; oi < 14; oi++) {
        int o = quad * 14 + oi;
        float lbv = accl[oi];
        float ge = 0.5f * lbv * (1.f + erff(lbv * 0.70710678118654752f));
        outp[((o * NBD + z) * HH + oy) * WW + ox] = accx[oi] * ge + xres[oi];
    }
}

// =====================================================================
extern "C" void kernel_launch(void* const* d_in, const int* in_sizes, int n_in,
                              void* d_out, int out_size, void* d_ws, size_t ws_size,
                              hipStream_t stream)
{
    (void)in_sizes; (void)n_in; (void)out_size; (void)ws_size;
    const float* x         = (const float*)d_in[0];
    const float* last      = (const float*)d_in[1];
    const float* fa_ln_w   = (const float*)d_in[2];
    const float* fa_ln_b   = (const float*)d_in[3];
    const float* fa_qk_w   = (const float*)d_in[4];
    const float* fa_v_w    = (const float*)d_in[5];
    const float* fa_out_w  = (const float*)d_in[6];
    const float* fa_out_b  = (const float*)d_in[7];
    const float* fa_pcq_w  = (const float*)d_in[8];
    const float* fa_pcq_b  = (const float*)d_in[9];
    const float* fa_pck_w  = (const float*)d_in[10];
    const float* fa_pck_b  = (const float*)d_in[11];
    const float* fa_m1_w   = (const float*)d_in[12];
    const float* fa_m2a_w  = (const float*)d_in[13];
    const float* fa_m2b_w  = (const float*)d_in[14];
    const float* sca_ln1_w = (const float*)d_in[15];
    const float* sca_ln1_b = (const float*)d_in[16];
    const float* sca_ln2_w = (const float*)d_in[17];
    const float* sca_ln2_b = (const float*)d_in[18];
    const float* sca_q_w   = (const float*)d_in[19];
    const float* sca_k_w   = (const float*)d_in[20];
    const float* sca_v_w   = (const float*)d_in[21];
    const float* sca_out_w = (const float*)d_in[22];
    const float* sca_pcq_w = (const float*)d_in[23];
    const float* sca_pcq_b = (const float*)d_in[24];
    const float* sca_pck_w = (const float*)d_in[25];
    const float* sca_pck_b = (const float*)d_in[26];
    const float* sca_m1_w  = (const float*)d_in[27];
    const float* sca_m2a_w = (const float*)d_in[28];
    const float* sca_m2b_w = (const float*)d_in[29];
    const float* ffn_ln1_w = (const float*)d_in[30];
    const float* ffn_ln1_b = (const float*)d_in[31];
    const float* ffn_ln2_w = (const float*)d_in[32];
    const float* ffn_ln2_b = (const float*)d_in[33];
    const float* ffn_x1_w  = (const float*)d_in[34];
    const float* ffn_x2_w  = (const float*)d_in[35];
    const float* ffn_l1_w  = (const float*)d_in[36];
    const float* ffn_l2_w  = (const float*)d_in[37];
    float* out = (float*)d_out;
    float* ws  = (float*)d_ws;

    const size_t FULL = (size_t)CH * S3;      // 16,515,072
    const size_t HALF = (size_t)DHALF * S3;   //  8,257,536
    float* x1    = ws;                        // FA output
    float* lnbuf = ws + FULL;                 // LN scratch, later aliased as x2
    float* qb    = lnbuf + FULL;
    float* kb    = qb + HALF;
    float* vb    = kb + HALF;
    float* weff  = vb + HALF;                 // 56448 floats
    float* x2    = lnbuf;                     // free after convs -> SCA output

    // --- FFN weight collapse (independent; run first) ---
    ffn_wprep_kernel<<<dim3((2 * 28224 + 255) / 256), dim3(256), 0, stream>>>(
        ffn_x1_w, ffn_x2_w, ffn_l1_w, ffn_l2_w, weff);

    // --- FA ---
    fa_kernel<<<dim3(4608), dim3(256), 0, stream>>>(
        x, fa_ln_w, fa_ln_b, fa_qk_w, fa_v_w, fa_out_w, fa_out_b,
        fa_pcq_w, fa_pcq_b, fa_pck_w, fa_pck_b, fa_m1_w, fa_m2a_w, fa_m2b_w, x1);

    // --- SCA: LN + grouped convs (one LN scratch, reused) ---
    ln_kernel<<<dim3(S3 / 256), dim3(256), 0, stream>>>(x1, sca_ln1_w, sca_ln1_b, lnbuf);
    conv3_kernel<<<dim3(DHALF * S3 / 256), dim3(256), 0, stream>>>(lnbuf, sca_q_w, qb);
    ln_kernel<<<dim3(S3 / 256), dim3(256), 0, stream>>>(last, sca_ln2_w, sca_ln2_b, lnbuf);
    conv3_kernel<<<dim3(DHALF * S3 / 256), dim3(256), 0, stream>>>(lnbuf, sca_k_w, kb);
    conv3_kernel<<<dim3(DHALF * S3 / 256), dim3(256), 0, stream>>>(lnbuf, sca_v_w, vb);

    sca_kernel<<<dim3(4608), dim3(256), 0, stream>>>(
        qb, kb, vb, x1, sca_out_w,
        sca_pcq_w, sca_pcq_b, sca_pck_w, sca_pck_b, sca_m1_w, sca_m2a_w, sca_m2b_w, x2);

    // --- FFN (LN fused inside) ---
    ffn_kernel<<<dim3(4608), dim3(256), 0, stream>>>(
        x2, last, ffn_ln1_w, ffn_ln1_b, ffn_ln2_w, ffn_ln2_b, weff, out);
}

// Round 4
// 1690.537 us; speedup vs baseline: 1.7944x; 1.4391x over previous
//
#include <hip/hip_runtime.h>
#include <math.h>

// ---- problem constants ----
#define CH 56          // channels
#define NBD 8          // "B" depth dim
#define HH 192
#define WW 192
#define PLANE (HH*WW)          // 36864
#define S3 (NBD*PLANE)         // 294912 positions per channel
#define NWX 24                 // windows per row/col
#define NTOK 64                // tokens per window
#define DHALF 28               // q/k/v channels
#define DHEAD 14               // per-head dim
// LDS padded strides (bank-conflict avoidance)
#define XNP 57
#define QKP 29
#define SIMP 65
// FFN MFMA halo: per-branch LDS bytes (100 pixels * 64 ch * 2B)
#define FFN_BR_OFF 12800

typedef __attribute__((ext_vector_type(8))) short short8;
typedef __attribute__((ext_vector_type(4))) float f32x4;

__device__ __forceinline__ int gidx(int c, int b, int y, int x) {
    return ((c * NBD + b) * HH + y) * WW + x;
}

__device__ __forceinline__ unsigned short f2bf(float f) {
    unsigned int u = __float_as_uint(f);
    u = (u + 0x7FFFu + ((u >> 16) & 1u)) >> 16;   // RNE
    return (unsigned short)u;
}

// =====================================================================
// Kernel 1: FA — fused PreNorm + windowed self-attention, per (window,b)
// =====================================================================
__global__ __launch_bounds__(256) void fa_kernel(
    const float* __restrict__ x,
    const float* __restrict__ lnw, const float* __restrict__ lnb,
    const float* __restrict__ qkw, const float* __restrict__ vw,
    const float* __restrict__ ow,  const float* __restrict__ ob,
    const float* __restrict__ pcqw, const float* __restrict__ pcqb,
    const float* __restrict__ pckw, const float* __restrict__ pckb,
    const float* __restrict__ m1,  const float* __restrict__ m2a,
    const float* __restrict__ m2b,
    float* __restrict__ x1)
{
    __shared__ float s_xn[NTOK * XNP];
    __shared__ float s_w[56*56 + 28*56];
    __shared__ float s_q[NTOK * QKP];
    __shared__ float s_k[NTOK * QKP];
    __shared__ float s_v[NTOK * QKP];
    __shared__ float s_sim[NTOK * SIMP];
    __shared__ float s_o[NTOK * DHALF];
    __shared__ float s_mu[NTOK], s_rs[NTOK];
    __shared__ float s_Sq[NTOK], s_Sk[NTOK], s_t[NTOK], s_t2[NTOK];
    __shared__ float s_theta;

    const int tid = threadIdx.x;
    const int b   = blockIdx.x & 7;
    const int win = blockIdx.x >> 3;
    const int y0  = (win / NWX) * 8;
    const int x0  = (win % NWX) * 8;

    for (int i = tid; i < NTOK * CH; i += 256) {
        int c = i >> 6, tok = i & 63;
        s_xn[tok * XNP + c] = x[gidx(c, b, y0 + (tok >> 3), x0 + (tok & 7))];
    }
    for (int i = tid; i < 84 * 56; i += 256)
        s_w[i] = (i < 3136) ? qkw[i] : vw[i - 3136];
    __syncthreads();

    if (tid < NTOK) {
        float mu = 0.f;
        #pragma unroll
        for (int c = 0; c < CH; c++) mu += s_xn[tid * XNP + c];
        mu *= (1.f / CH);
        float var = 0.f;
        #pragma unroll
        for (int c = 0; c < CH; c++) { float d = s_xn[tid * XNP + c] - mu; var += d * d; }
        var *= (1.f / CH);
        s_mu[tid] = mu;
        s_rs[tid] = rsqrtf(var + 1e-5f);
    }
    __syncthreads();
    for (int i = tid; i < NTOK * CH; i += 256) {
        int c = i >> 6, tok = i & 63;
        s_xn[tok * XNP + c] = (s_xn[tok * XNP + c] - s_mu[tok]) * s_rs[tok] * lnw[c] + lnb[c];
    }
    __syncthreads();

    for (int i = tid; i < NTOK * 84; i += 256) {
        int o = i >> 6, tok = i & 63;
        const float* wr = &s_w[o * 56];
        float acc = 0.f;
        #pragma unroll
        for (int c = 0; c < CH; c++) acc += s_xn[tok * XNP + c] * wr[c];
        if (o < 28)       s_q[tok * QKP + o]        = acc;
        else if (o < 56)  s_k[tok * QKP + (o - 28)] = acc;
        else              s_v[tok * QKP + (o - 56)] = acc;
    }
    __syncthreads();
    for (int i = tid; i < 56 * 28; i += 256) s_w[i] = ow[i];

    for (int h = 0; h < 2; h++) {
        const int ho = h * DHEAD;
        if (tid < NTOK) {
            float a = pcqb[0];
            #pragma unroll
            for (int d = 0; d < DHEAD; d++) a += s_q[tid * QKP + ho + d] * pcqw[d];
            s_Sq[tid] = a;
        } else if (tid < 2 * NTOK) {
            int j = tid - NTOK;
            float a = pckb[0];
            #pragma unroll
            for (int d = 0; d < DHEAD; d++) a += s_k[j * QKP + ho + d] * pckw[d];
            s_Sk[j] = a;
        }
        __syncthreads();
        for (int i = tid; i < NTOK * NTOK; i += 256) {
            int r = i >> 6, j = i & 63;
            float a = 0.f;
            #pragma unroll
            for (int d = 0; d < DHEAD; d++)
                a += s_q[r * QKP + ho + d] * s_k[j * QKP + ho + d];
            s_sim[r * SIMP + j] = a;
        }
        __syncthreads();
        if (tid < NTOK) {
            float a = 0.f;
            for (int j = 0; j < NTOK; j++)
                if (j != tid) a += s_sim[tid * SIMP + j] * m1[j];
            s_t[tid] = a;
        }
        __syncthreads();
        if (tid < NTOK) {
            float a = 0.f;
            for (int i2 = 0; i2 < NTOK; i2++) a += s_t[i2] * m2a[tid * 64 + i2];
            s_t2[tid] = (a > 0.f) ? a : 0.1f * a;
        }
        __syncthreads();
        if (tid == 0) {
            float a = 0.f;
            for (int j = 0; j < NTOK; j++) a += s_t2[j] * m2b[j];
            s_theta = a;
        }
        __syncthreads();
        if (tid < NTOK) {
            const float Sqi = s_Sq[tid];
            float m = -1e30f;
            for (int j = 0; j < NTOK; j++) {
                float s = s_sim[tid * SIMP + j] * Sqi * s_Sk[j];
                s_sim[tid * SIMP + j] = s;
                m = fmaxf(m, s);
            }
            float sum = 0.f;
            for (int j = 0; j < NTOK; j++) sum += expf(s_sim[tid * SIMP + j] - m);
            const float inv = 1.f / sum, th = s_theta;
            for (int j = 0; j < NTOK; j++) {
                float s = s_sim[tid * SIMP + j];
                s_sim[tid * SIMP + j] = (s > th) ? expf(s - m) * inv : 0.f;
            }
        }
        __syncthreads();
        for (int i = tid; i < NTOK * DHEAD; i += 256) {
            int r = i / DHEAD, d = i - r * DHEAD;
            float a = 0.f;
            #pragma unroll
            for (int j = 0; j < NTOK; j++)
                a += s_sim[r * SIMP + j] * s_v[j * QKP + ho + d];
            s_o[r * DHALF + ho + d] = a;
        }
        __syncthreads();
    }

    for (int i = tid; i < NTOK * CH; i += 256) {
        int c = i >> 6, tok = i & 63;
        float a = ob[c];
        #pragma unroll
        for (int o = 0; o < DHALF; o++) a += s_o[tok * DHALF + o] * s_w[c * DHALF + o];
        int g = gidx(c, b, y0 + (tok >> 3), x0 + (tok & 7));
        x1[g] = a + x[g];
    }
}

// =====================================================================
// Kernel 2: LayerNorm over channel dim, fp32 out (for SCA convs)
// =====================================================================
__global__ __launch_bounds__(256) void ln_kernel(
    const float* __restrict__ in, const float* __restrict__ w,
    const float* __restrict__ b, float* __restrict__ outp)
{
    int p = blockIdx.x * 256 + threadIdx.x;
    if (p >= S3) return;
    float v[CH];
    float mu = 0.f;
    #pragma unroll
    for (int c = 0; c < CH; c++) { v[c] = in[(size_t)c * S3 + p]; mu += v[c]; }
    mu *= (1.f / CH);
    float var = 0.f;
    #pragma unroll
    for (int c = 0; c < CH; c++) { float d = v[c] - mu; var += d * d; }
    float rs = rsqrtf(var * (1.f / CH) + 1e-5f);
    #pragma unroll
    for (int c = 0; c < CH; c++)
        outp[(size_t)c * S3 + p] = (v[c] - mu) * rs * w[c] + b[c];
}

// =====================================================================
// Kernel 2b: LayerNorm -> bf16, channel-innermost [p][56] (for FFN MFMA)
// =====================================================================
__global__ __launch_bounds__(256) void ln_bf16_kernel(
    const float* __restrict__ in, const float* __restrict__ w,
    const float* __restrict__ b, unsigned short* __restrict__ outp)
{
    int p = blockIdx.x * 256 + threadIdx.x;
    if (p >= S3) return;
    float v[CH];
    float mu = 0.f;
    #pragma unroll
    for (int c = 0; c < CH; c++) { v[c] = in[(size_t)c * S3 + p]; mu += v[c]; }
    mu *= (1.f / CH);
    float var = 0.f;
    #pragma unroll
    for (int c = 0; c < CH; c++) { float d = v[c] - mu; var += d * d; }
    float rs = rsqrtf(var * (1.f / CH) + 1e-5f);
    unsigned int q[28];
    #pragma unroll
    for (int c = 0; c < CH; c += 2) {
        float a0 = (v[c]     - mu) * rs * w[c]     + b[c];
        float a1 = (v[c + 1] - mu) * rs * w[c + 1] + b[c + 1];
        q[c >> 1] = (unsigned int)f2bf(a0) | ((unsigned int)f2bf(a1) << 16);
    }
    uint4* dst = (uint4*)(outp + (size_t)p * 56);
    #pragma unroll
    for (int k = 0; k < 7; k++) {
        uint4 t; t.x = q[k*4]; t.y = q[k*4+1]; t.z = q[k*4+2]; t.w = q[k*4+3];
        dst[k] = t;
    }
}

// =====================================================================
// Kernel 3: grouped 3x3x3 conv, 2-in -> 1-out per group (28 out ch)
// =====================================================================
__global__ __launch_bounds__(256) void conv3_kernel(
    const float* __restrict__ in, const float* __restrict__ w,
    float* __restrict__ outp)
{
    int n = blockIdx.x * 256 + threadIdx.x;
    if (n >= DHALF * S3) return;
    int o = n / S3;
    int r = n - o * S3;
    int z = r / PLANE;
    int t = r - z * PLANE;
    int y = t / WW;
    int xx = t - y * WW;
    float acc = 0.f;
    #pragma unroll
    for (int ic = 0; ic < 2; ic++) {
        const float* ip = in + (size_t)(2 * o + ic) * S3;
        const float* wp = w + (o * 2 + ic) * 27;
        #pragma unroll
        for (int dz = 0; dz < 3; dz++) {
            int zz = z + dz - 1;
            if (zz < 0 || zz >= NBD) continue;
            #pragma unroll
            for (int dy = 0; dy < 3; dy++) {
                int yy = y + dy - 1;
                if (yy < 0 || yy >= HH) continue;
                #pragma unroll
                for (int dx = 0; dx < 3; dx++) {
                    int xc = xx + dx - 1;
                    if (xc < 0 || xc >= WW) continue;
                    acc += ip[zz * PLANE + yy * WW + xc] * wp[dz * 9 + dy * 3 + dx];
                }
            }
        }
    }
    outp[n] = acc;
}

// =====================================================================
// Kernel 4: SCA — windowed cross-attention on precomputed q,k,v
// =====================================================================
__global__ __launch_bounds__(256) void sca_kernel(
    const float* __restrict__ qb, const float* __restrict__ kb,
    const float* __restrict__ vb, const float* __restrict__ x1,
    const float* __restrict__ ocw,
    const float* __restrict__ pcqw, const float* __restrict__ pcqb,
    const float* __restrict__ pckw, const float* __restrict__ pckb,
    const float* __restrict__ m1,  const float* __restrict__ m2a,
    const float* __restrict__ m2b,
    float* __restrict__ x2)
{
    __shared__ float s_q[NTOK * QKP];
    __shared__ float s_k[NTOK * QKP];
    __shared__ float s_v[NTOK * QKP];
    __shared__ float s_sim[NTOK * SIMP];
    __shared__ float s_o[NTOK * DHALF];
    __shared__ float s_Sq[NTOK], s_Sk[NTOK], s_t[NTOK], s_t2[NTOK];
    __shared__ float s_theta;

    const int tid = threadIdx.x;
    const int b   = blockIdx.x & 7;
    const int win = blockIdx.x >> 3;
    const int y0  = (win / NWX) * 8;
    const int x0  = (win % NWX) * 8;

    for (int i = tid; i < NTOK * DHALF; i += 256) {
        int o = i >> 6, tok = i & 63;
        int g = ((o * NBD + b) * HH + y0 + (tok >> 3)) * WW + x0 + (tok & 7);
        s_q[tok * QKP + o] = qb[g];
        s_k[tok * QKP + o] = kb[g];
        s_v[tok * QKP + o] = vb[g];
    }
    __syncthreads();

    for (int h = 0; h < 2; h++) {
        const int ho = h * DHEAD;
        if (tid < NTOK) {
            float a = pcqb[0];
            #pragma unroll
            for (int d = 0; d < DHEAD; d++) a += s_q[tid * QKP + ho + d] * pcqw[d];
            s_Sq[tid] = a;
        } else if (tid < 2 * NTOK) {
            int j = tid - NTOK;
            float a = pckb[0];
            #pragma unroll
            for (int d = 0; d < DHEAD; d++) a += s_k[j * QKP + ho + d] * pckw[d];
            s_Sk[j] = a;
        }
        __syncthreads();
        for (int i = tid; i < NTOK * NTOK; i += 256) {
            int r = i >> 6, j = i & 63;
            float a = 0.f;
            #pragma unroll
            for (int d = 0; d < DHEAD; d++)
                a += s_q[r * QKP + ho + d] * s_k[j * QKP + ho + d];
            s_sim[r * SIMP + j] = a;
        }
        __syncthreads();
        if (tid < NTOK) {
            float a = 0.f;
            for (int j = 0; j < NTOK; j++)
                if (j != tid) a += s_sim[tid * SIMP + j] * m1[j];
            s_t[tid] = a;
        }
        __syncthreads();
        if (tid < NTOK) {
            float a = 0.f;
            for (int i2 = 0; i2 < NTOK; i2++) a += s_t[i2] * m2a[tid * 64 + i2];
            s_t2[tid] = (a > 0.f) ? a : 0.1f * a;
        }
        __syncthreads();
        if (tid == 0) {
            float a = 0.f;
            for (int j = 0; j < NTOK; j++) a += s_t2[j] * m2b[j];
            s_theta = a;
        }
        __syncthreads();
        if (tid < NTOK) {
            const float Sqi = s_Sq[tid];
            float m = -1e30f;
            for (int j = 0; j < NTOK; j++) {
                float s = s_sim[tid * SIMP + j] * Sqi * s_Sk[j];
                s_sim[tid * SIMP + j] = s;
                m = fmaxf(m, s);
            }
            float sum = 0.f;
            for (int j = 0; j < NTOK; j++) sum += expf(s_sim[tid * SIMP + j] - m);
            const float inv = 1.f / sum, th = s_theta;
            for (int j = 0; j < NTOK; j++) {
                float s = s_sim[tid * SIMP + j];
                s_sim[tid * SIMP + j] = (s > th) ? expf(s - m) * inv : 0.f;
            }
        }
        __syncthreads();
        for (int i = tid; i < NTOK * DHEAD; i += 256) {
            int r = i / DHEAD, d = i - r * DHEAD;
            float a = 0.f;
            #pragma unroll
            for (int j = 0; j < NTOK; j++)
                a += s_sim[r * SIMP + j] * s_v[j * QKP + ho + d];
            s_o[r * DHALF + ho + d] = a;
        }
        __syncthreads();
    }

    for (int i = tid; i < NTOK * CH; i += 256) {
        int c = i >> 6, tok = i & 63;
        int g = gidx(c, b, y0 + (tok >> 3), x0 + (tok & 7));
        x2[g] = s_o[tok * DHALF + (c >> 1)] * ocw[c] + x1[g];
    }
}

// =====================================================================
// Kernel 5a: collapse FFN weights + emit pre-swizzled bf16 A-fragments.
// frag f = br*72 + tap*8 + m*2 + ks; 64 lanes x 8 bf16 each.
// lane: row = lane&15 (o = m*16+row), k = ks*32 + (lane>>4)*8 + j (ch c).
// =====================================================================
__global__ __launch_bounds__(256) void ffn_wprep_frag_kernel(
    const float* __restrict__ w1x, const float* __restrict__ w2x,
    const float* __restrict__ w1l, const float* __restrict__ w2l,
    unsigned short* __restrict__ wfrag)
{
    int idx = blockIdx.x * 256 + threadIdx.x;     // (f, lane)
    if (idx >= 144 * 64) return;
    int f = idx >> 6, lane = idx & 63;
    int br = f / 72;
    int r  = f - br * 72;
    int tap = r >> 3;
    int m   = (r & 7) >> 1;
    int ks  = r & 1;
    const float* w1 = br ? w1l : w1x;
    const float* w2 = br ? w2l : w2x;
    int o  = m * 16 + (lane & 15);
    int c0 = ks * 32 + (lane >> 4) * 8;
    unsigned short vals[8];
    #pragma unroll
    for (int j = 0; j < 8; j++) {
        int c = c0 + j;
        float a = 0.f;
        if (o < 56 && c < 56) {
            #pragma unroll
            for (int jj = 0; jj < 4; jj++)
                a += w2[(o * 4 + jj) * 9 + tap] * w1[(o * 4 + jj) * 56 + c];
        }
        vals[j] = f2bf(a);
    }
    uint4 packed;
    packed.x = (unsigned int)vals[0] | ((unsigned int)vals[1] << 16);
    packed.y = (unsigned int)vals[2] | ((unsigned int)vals[3] << 16);
    packed.z = (unsigned int)vals[4] | ((unsigned int)vals[5] << 16);
    packed.w = (unsigned int)vals[6] | ((unsigned int)vals[7] << 16);
    *(uint4*)(wfrag + (size_t)idx * 8) = packed;
}

// =====================================================================
// Kernel 5b: FFN via MFMA — 9 shifted GEMMs on bf16 LN'd inputs.
// Block = (z, 8x8 tile); 4 waves = 4 M-tiles (16 out-ch each).
// LDS: both branches' 10x10 halos, [pix][64ch] bf16, XOR slot-swizzled.
// Branch br lives at byte offset br*FFN_BR_OFF (write AND read).
// =====================================================================
__global__ __launch_bounds__(256) void ffn_mfma_kernel(
    const unsigned short* __restrict__ xnb,   // LN'd x2, bf16 [p][56]
    const unsigned short* __restrict__ lnb,   // LN'd last, bf16 [p][56]
    const unsigned short* __restrict__ wfrag, // A-fragments
    const float* __restrict__ x2,             // residual fp32 [c][p]
    float* __restrict__ outp)
{
    __shared__ unsigned short s_t[2 * 100 * 64];   // 25.6 KB

    const int tid = threadIdx.x;
    const int z  = blockIdx.x / 576;
    const int t  = blockIdx.x % 576;
    const int ty = t / 24, tx = t % 24;
    const int y0 = ty * 8, x0 = tx * 8;

    // ---- stage halos (1600 16B chunks; chunk 7 = zero-pad ch 56..63) ----
    for (int i = tid; i < 1600; i += 256) {
        int br = i / 800;
        int r  = i - br * 800;
        int hp = r >> 3, ck = r & 7;
        int hy = hp / 10, hx = hp - hy * 10;
        int y = y0 + hy - 1, xx = x0 + hx - 1;
        uint4 v = {0u, 0u, 0u, 0u};
        if (ck < 7 && y >= 0 && y < HH && xx >= 0 && xx < WW) {
            const unsigned short* src = (br ? lnb : xnb) +
                (size_t)(z * PLANE + y * WW + xx) * 56 + ck * 8;
            v = *(const uint4*)src;
        }
        unsigned int byte = (unsigned int)(br * FFN_BR_OFF + hp * 128 + ((ck ^ (hp & 7)) << 4));
        *(uint4*)((char*)s_t + byte) = v;
    }
    __syncthreads();

    // ---- MFMA: wave = mtile; 9 taps x 4 ntiles x 2 ksteps x 2 branches ----
    const int wid  = tid >> 6;          // mtile 0..3
    const int lane = tid & 63;
    const int col  = lane & 15;
    const int grp  = lane >> 4;

    f32x4 accx[4], accl[4];
    #pragma unroll
    for (int n = 0; n < 4; n++) {
        accx[n] = (f32x4){0.f, 0.f, 0.f, 0.f};
        accl[n] = (f32x4){0.f, 0.f, 0.f, 0.f};
    }

    const short8* wf = (const short8*)wfrag;

    for (int tap = 0; tap < 9; tap++) {
        int dy = tap / 3, dx = tap - dy * 3;
        short8 ax0 = wf[(tap * 8 + wid * 2 + 0) * 64 + lane];
        short8 ax1 = wf[(tap * 8 + wid * 2 + 1) * 64 + lane];
        short8 al0 = wf[(72 + tap * 8 + wid * 2 + 0) * 64 + lane];
        short8 al1 = wf[(72 + tap * 8 + wid * 2 + 1) * 64 + lane];
        #pragma unroll
        for (int nt = 0; nt < 4; nt++) {
            int pix = nt * 16 + col;
            int py = pix >> 3, px = pix & 7;
            int hp = (py + dy) * 10 + (px + dx);
            unsigned int base = (unsigned int)(hp * 128);
            unsigned int sw = (unsigned int)(hp & 7);
            // kstep 0: channel chunks 0..3 -> chunk index grp
            unsigned int o0 = base + (((0u * 4u + grp) ^ sw) << 4);
            short8 bx0 = *(const short8*)((const char*)s_t + o0);
            short8 bl0 = *(const short8*)((const char*)s_t + FFN_BR_OFF + o0);
            accx[nt] = __builtin_amdgcn_mfma_f32_16x16x32_bf16(ax0, bx0, accx[nt], 0, 0, 0);
            accl[nt] = __builtin_amdgcn_mfma_f32_16x16x32_bf16(al0, bl0, accl[nt], 0, 0, 0);
            // kstep 1: channel chunks 4..7 -> chunk index 4+grp
            unsigned int o1 = base + (((1u * 4u + grp) ^ sw) << 4);
            short8 bx1 = *(const short8*)((const char*)s_t + o1);
            short8 bl1 = *(const short8*)((const char*)s_t + FFN_BR_OFF + o1);
            accx[nt] = __builtin_amdgcn_mfma_f32_16x16x32_bf16(ax1, bx1, accx[nt], 0, 0, 0);
            accl[nt] = __builtin_amdgcn_mfma_f32_16x16x32_bf16(al1, bl1, accl[nt], 0, 0, 0);
        }
    }

    // ---- epilogue: GELU gate + residual; D layout col=lane&15, row=(lane>>4)*4+reg ----
    #pragma unroll
    for (int nt = 0; nt < 4; nt++) {
        int pix = nt * 16 + col;
        int py = pix >> 3, px = pix & 7;
        int p = z * PLANE + (y0 + py) * WW + (x0 + px);
        #pragma unroll
        for (int reg = 0; reg < 4; reg++) {
            int o = wid * 16 + grp * 4 + reg;
            if (o < 56) {
                float lv = accl[nt][reg];
                float ge = 0.5f * lv * (1.f + erff(lv * 0.70710678118654752f));
                size_t g = (size_t)o * S3 + p;
                outp[g] = accx[nt][reg] * ge + x2[g];
            }
        }
    }
}

// =====================================================================
extern "C" void kernel_launch(void* const* d_in, const int* in_sizes, int n_in,
                              void* d_out, int out_size, void* d_ws, size_t ws_size,
                              hipStream_t stream)
{
    (void)in_sizes; (void)n_in; (void)out_size; (void)ws_size;
    const float* x         = (const float*)d_in[0];
    const float* last      = (const float*)d_in[1];
    const float* fa_ln_w   = (const float*)d_in[2];
    const float* fa_ln_b   = (const float*)d_in[3];
    const float* fa_qk_w   = (const float*)d_in[4];
    const float* fa_v_w    = (const float*)d_in[5];
    const float* fa_out_w  = (const float*)d_in[6];
    const float* fa_out_b  = (const float*)d_in[7];
    const float* fa_pcq_w  = (const float*)d_in[8];
    const float* fa_pcq_b  = (const float*)d_in[9];
    const float* fa_pck_w  = (const float*)d_in[10];
    const float* fa_pck_b  = (const float*)d_in[11];
    const float* fa_m1_w   = (const float*)d_in[12];
    const float* fa_m2a_w  = (const float*)d_in[13];
    const float* fa_m2b_w  = (const float*)d_in[14];
    const float* sca_ln1_w = (const float*)d_in[15];
    const float* sca_ln1_b = (const float*)d_in[16];
    const float* sca_ln2_w = (const float*)d_in[17];
    const float* sca_ln2_b = (const float*)d_in[18];
    const float* sca_q_w   = (const float*)d_in[19];
    const float* sca_k_w   = (const float*)d_in[20];
    const float* sca_v_w   = (const float*)d_in[21];
    const float* sca_out_w = (const float*)d_in[22];
    const float* sca_pcq_w = (const float*)d_in[23];
    const float* sca_pcq_b = (const float*)d_in[24];
    const float* sca_pck_w = (const float*)d_in[25];
    const float* sca_pck_b = (const float*)d_in[26];
    const float* sca_m1_w  = (const float*)d_in[27];
    const float* sca_m2a_w = (const float*)d_in[28];
    const float* sca_m2b_w = (const float*)d_in[29];
    const float* ffn_ln1_w = (const float*)d_in[30];
    const float* ffn_ln1_b = (const float*)d_in[31];
    const float* ffn_ln2_w = (const float*)d_in[32];
    const float* ffn_ln2_b = (const float*)d_in[33];
    const float* ffn_x1_w  = (const float*)d_in[34];
    const float* ffn_x2_w  = (const float*)d_in[35];
    const float* ffn_l1_w  = (const float*)d_in[36];
    const float* ffn_l2_w  = (const float*)d_in[37];
    float* out = (float*)d_out;
    float* ws  = (float*)d_ws;

    const size_t FULL = (size_t)CH * S3;      // 16,515,072 floats
    const size_t HALF = (size_t)DHALF * S3;
    float* x1    = ws;                        // FA output (freed after sca)
    float* lnbuf = ws + FULL;                 // LN scratch -> x2
    float* qb    = lnbuf + FULL;
    float* kb    = qb + HALF;
    float* vb    = kb + HALF;
    unsigned short* wfrag = (unsigned short*)(vb + HALF);  // 144*64*8 ush = 147 KB
    float* x2    = lnbuf;
    // after sca, x1's 66 MB region is reused for the two bf16 LN buffers:
    unsigned short* xnb = (unsigned short*)ws;         // bytes [0, 33MB)
    unsigned short* lnbb = (unsigned short*)ws + FULL; // bytes [33MB, 66MB)

    // --- FFN weight fragments (independent) ---
    ffn_wprep_frag_kernel<<<dim3(36), dim3(256), 0, stream>>>(
        ffn_x1_w, ffn_x2_w, ffn_l1_w, ffn_l2_w, wfrag);

    // --- FA ---
    fa_kernel<<<dim3(4608), dim3(256), 0, stream>>>(
        x, fa_ln_w, fa_ln_b, fa_qk_w, fa_v_w, fa_out_w, fa_out_b,
        fa_pcq_w, fa_pcq_b, fa_pck_w, fa_pck_b, fa_m1_w, fa_m2a_w, fa_m2b_w, x1);

    // --- SCA: LN + grouped convs ---
    ln_kernel<<<dim3(S3 / 256), dim3(256), 0, stream>>>(x1, sca_ln1_w, sca_ln1_b, lnbuf);
    conv3_kernel<<<dim3(DHALF * S3 / 256), dim3(256), 0, stream>>>(lnbuf, sca_q_w, qb);
    ln_kernel<<<dim3(S3 / 256), dim3(256), 0, stream>>>(last, sca_ln2_w, sca_ln2_b, lnbuf);
    conv3_kernel<<<dim3(DHALF * S3 / 256), dim3(256), 0, stream>>>(lnbuf, sca_k_w, kb);
    conv3_kernel<<<dim3(DHALF * S3 / 256), dim3(256), 0, stream>>>(lnbuf, sca_v_w, vb);

    sca_kernel<<<dim3(4608), dim3(256), 0, stream>>>(
        qb, kb, vb, x1, sca_out_w,
        sca_pcq_w, sca_pcq_b, sca_pck_w, sca_pck_b, sca_m1_w, sca_m2a_w, sca_m2b_w, x2);

    // --- FFN: LN->bf16 (x1 region now free), then MFMA conv ---
    ln_bf16_kernel<<<dim3(S3 / 256), dim3(256), 0, stream>>>(x2,   ffn_ln1_w, ffn_ln1_b, xnb);
    ln_bf16_kernel<<<dim3(S3 / 256), dim3(256), 0, stream>>>(last, ffn_ln2_w, ffn_ln2_b, lnbb);
    ffn_mfma_kernel<<<dim3(4608), dim3(256), 0, stream>>>(xnb, lnbb, wfrag, x2, out);
}